// Round 18
// baseline (127.610 us; speedup 1.0000x reference)
//
#include <hip/hip_runtime.h>
#include <hip/hip_bf16.h>

#define BATCH 2
#define SEQ 2048
#define EMBED 1024
#define HEADS 16
#define HD 64

typedef __attribute__((ext_vector_type(8))) short short8;
typedef __attribute__((ext_vector_type(4))) float f32x4;
typedef __attribute__((ext_vector_type(16))) float f32x16;
typedef __attribute__((ext_vector_type(4))) int i32x4;
typedef unsigned short u16;

// log2-domain softmax constants: scale' = 0.125*log2(e); mask' = -1e9*log2(e)
#define C2F 0.18033688f
#define NEGL -1442695040.0f

__device__ __forceinline__ u16 f2bf(float x){
  unsigned u = __builtin_bit_cast(unsigned, x);
  u = (u + 0x7fffu + ((u >> 16) & 1u)) >> 16;
  return (u16)u;
}

// raw v_exp_f32: valid here because inputs are either normal-range or hugely
// negative (masked: flush-to-zero is exactly the reference fp32 behavior).
__device__ __forceinline__ float fexp2(float x){
  float r;
  asm("v_exp_f32 %0, %1" : "=v"(r) : "v"(x));
  return r;
}

// async global->LDS, 16B per lane; dest = wave-uniform base + lane*16
__device__ __forceinline__ void gload16(const u16* g, u16* l){
  __builtin_amdgcn_global_load_lds(
      (const __attribute__((address_space(1))) unsigned int*)g,
      (__attribute__((address_space(3))) unsigned int*)l, 16, 0, 0);
}

// ---------------- x fp32 -> bf16 (vectorized) ----------------
__global__ void k_cvt(const float* __restrict__ in, u16* __restrict__ out){
  int i = blockIdx.x * blockDim.x + threadIdx.x;
  float4 v = reinterpret_cast<const float4*>(in)[i];
  ushort4 o;
  o.x = f2bf(v.x); o.y = f2bf(v.y); o.z = f2bf(v.z); o.w = f2bf(v.w);
  reinterpret_cast<ushort4*>(out)[i] = o;
}

// ---------------- transpose [K][N] fp32 -> [N][K] bf16 ----------------
__global__ void k_transpose(const float* __restrict__ in, u16* __restrict__ out,
                            int K, int N){
  __shared__ float tile[32][33];
  int n0 = blockIdx.x * 32, k0 = blockIdx.y * 32;
  int tx = threadIdx.x, ty = threadIdx.y;   // block (32,8)
  #pragma unroll
  for (int i = 0; i < 32; i += 8)
    tile[ty + i][tx] = in[(size_t)(k0 + ty + i) * N + n0 + tx];
  __syncthreads();
  #pragma unroll
  for (int i = 0; i < 32; i += 8)
    out[(size_t)(n0 + ty + i) * K + k0 + tx] = f2bf(tile[tx][ty + i]);
}

// ---------------- GEMM1: qkv = x@Wqkv + b ----------------
// BK=64 (half the barriers of BK=32; LDS unchanged since Cs dominates) +
// XCD-aware block remap (each XCD owns 4 contiguous mb-rows -> A-panels stay
// in its private L2). Q/K/V scattered into MFMA-FRAGMENT order via the
// LDS-staged full-line epilogue; Q pre-scaled by C2F.
__global__ __launch_bounds__(256) void k_gemm_qkv(
    const u16* __restrict__ A, const u16* __restrict__ Bt,
    const float* __restrict__ bias,
    u16* __restrict__ qb, u16* __restrict__ kbf, u16* __restrict__ vt)
{
  const int K = 1024;
  __shared__ __align__(16) u16 sbuf[128*144];   // As+Bs(32KB) / Cs(36.8KB)
  u16* As = sbuf;            // 128 x 64 u16
  u16* Bs = sbuf + 8192;     // 128 x 64 u16
  int t = threadIdx.x;
  int wave = t >> 6, lane = t & 63;
  int g = lane >> 4, c = lane & 15;
  int wr = wave >> 1, wc = wave & 1;
  // XCD remap: 768 blocks = 8 XCDs x 96 (= 4 mb-rows x 24 nb-cols each)
  int lin = blockIdx.x + 24 * blockIdx.y;
  int w   = (lin & 7) * 96 + (lin >> 3);
  int mb  = (w / 24) * 128, nb = (w % 24) * 128;

  // staging: 8 lanes per 64-u16 row; wave stages rows wave*32..wave*32+31
  const u16* ga = A  + (size_t)(mb + wave*32 + (lane>>3)) * K + (lane&7)*8;
  const u16* gb = Bt + (size_t)(nb + wave*32 + (lane>>3)) * K + (lane&7)*8;
  u16* la = &As[wave*2048];
  u16* lb = &Bs[wave*2048];

  f32x4 acc[4][4] = {};
  for (int k = 0; k < K; k += 64){
    #pragma unroll
    for (int rr = 0; rr < 4; rr++){
      gload16(ga + k + (size_t)rr*8*K, la + rr*512);
      gload16(gb + k + (size_t)rr*8*K, lb + rr*512);
    }
    __syncthreads();
    #pragma unroll
    for (int kk = 0; kk < 2; kk++){
      short8 af[4], bf[4];
      #pragma unroll
      for (int i = 0; i < 4; i++){
        af[i] = *reinterpret_cast<const short8*>(&As[(wr*64 + i*16 + c)*64 + kk*32 + 8*g]);
        bf[i] = *reinterpret_cast<const short8*>(&Bs[(wc*64 + i*16 + c)*64 + kk*32 + 8*g]);
      }
      #pragma unroll
      for (int i = 0; i < 4; i++)
        #pragma unroll
        for (int j = 0; j < 4; j++)
          acc[i][j] = __builtin_amdgcn_mfma_f32_16x16x32_bf16(af[i], bf[j], acc[i][j], 0, 0, 0);
    }
    __syncthreads();
  }

  // ---- stage C (bf16, bias added; Q cols pre-scaled by C2F) into LDS ----
  u16 (*Cs)[144] = (u16(*)[144])sbuf;
  #pragma unroll
  for (int i = 0; i < 4; i++)
  #pragma unroll
  for (int j = 0; j < 4; j++)
  #pragma unroll
  for (int r = 0; r < 4; r++){
    int row = wr*64 + i*16 + 4*g + r;
    int col = wc*64 + j*16 + c;
    int gcol = nb + col;
    float vv = acc[i][j][r] + bias[gcol];
    if ((gcol % 192) < 64) vv *= C2F;     // Q column
    Cs[row][col] = f2bf(vv);
  }
  __syncthreads();

  // ---- fragment-run writes: 32 cells x 64 runs of 16B ----
  int b  = mb >> 11;
  int sb = mb & 2047;
  for (int cell = wave; cell < 32; cell += 4){
    int s32 = cell >> 3;          // 0..3 (32-row group)
    int cg  = cell & 7;           // 0..7 (16-col group)
    int col0 = nb + cg*16;
    int h   = col0 / 192;
    int rem = col0 - h*192;
    int sel = rem >> 6;
    int d0  = rem & 63;           // 16-aligned
    size_t hb = (size_t)(b * HEADS + h);
    if (sel < 2){
      int sl  = lane & 31;
      int dhi = lane >> 5;
      int s   = sb + s32*32 + sl;
      size_t off = (((hb*64 + (size_t)(s>>5))*4 + (size_t)(d0>>4))*64 + (size_t)lane)*8;
      const short8 v = *reinterpret_cast<const short8*>(&Cs[s32*32 + sl][cg*16 + dhi*8]);
      u16* dst = (sel == 0 ? qb : kbf) + off;
      *reinterpret_cast<short8*>(dst) = v;
    } else {
      int dl   = lane & 15;
      int soct = lane >> 4;       // 0..3
      int d    = d0 + dl;
      int sl0  = s32*32 + soct*8;
      int s0   = sb + sl0;
      int lanep = (d & 31) | (((s0 >> 3) & 1) << 5);
      size_t off = (((hb*128 + (size_t)(s0>>4))*2 + (size_t)(d>>5))*64 + (size_t)lanep)*8;
      u16 tmp[8];
      #pragma unroll
      for (int k2 = 0; k2 < 8; k2++) tmp[k2] = Cs[sl0 + k2][cg*16 + dl];
      *reinterpret_cast<short8*>(vt + off) = *reinterpret_cast<const short8*>(tmp);
    }
  }
}

// ---------------- P-fragment pack: cvt_pk + permlane32_swap (T12) ----------------
template<int B>
__device__ __forceinline__ short8 pack_pa(const f32x16& p){
  unsigned X, Y, Z, W;
  asm("v_cvt_pk_bf16_f32 %0, %1, %2" : "=v"(X) : "v"(p[B+0]), "v"(p[B+1]));
  asm("v_cvt_pk_bf16_f32 %0, %1, %2" : "=v"(Y) : "v"(p[B+2]), "v"(p[B+3]));
  asm("v_cvt_pk_bf16_f32 %0, %1, %2" : "=v"(Z) : "v"(p[B+4]), "v"(p[B+5]));
  asm("v_cvt_pk_bf16_f32 %0, %1, %2" : "=v"(W) : "v"(p[B+6]), "v"(p[B+7]));
  asm("v_permlane32_swap_b32 %0, %1" : "+v"(X), "+v"(Z));
  asm("v_permlane32_swap_b32 %0, %1" : "+v"(Y), "+v"(W));
  i32x4 w = { (int)X, (int)Y, (int)Z, (int)W };
  return __builtin_bit_cast(short8, w);
}

// ---------------- fused anti-causal flash attention, swapped-QK 32x32 ----------
// (unchanged from round 16 — best passing version)
__global__ __launch_bounds__(256) void k_attn(
    const u16* __restrict__ qb, const u16* __restrict__ kbuf,
    const u16* __restrict__ vt, u16* __restrict__ vals)
{
  __shared__ __align__(16) u16 po[4][32][72];   // bf16 partial O, row-padded
  __shared__ float pmv[4][32];
  __shared__ float plv[4][32];

  int wave = threadIdx.x >> 6, lane = threadIdx.x & 63;
  int hi = lane >> 5, ln = lane & 31;
  int d0 = blockIdx.x;
  int x   = d0 & 7;
  int kk  = d0 >> 3;            // [0,256)
  int grp = kk >> 6;            // [0,4)
  int qr  = kk & 63;
  int qidx = (qr == 0) ? 63 : qr - 1;
  int bh  = x + 8 * grp;
  int qw  = qidx * 32;
  int qg  = qw + ln;

  // fragment-space base pointers (each bh = 256 tiles x 512 u16 = 256KB)
  const u16* Qf = qb   + (size_t)bh*131072 + ((size_t)(qw>>5)*4)*512 + (size_t)lane*8;
  const u16* Kf = kbuf + (size_t)bh*131072 + (size_t)lane*8;
  const u16* Vf = vt   + (size_t)bh*131072 + (size_t)lane*8;

  short8 qf[4];
  #pragma unroll
  for (int kc = 0; kc < 4; kc++)
    qf[kc] = *reinterpret_cast<const short8*>(Qf + (size_t)kc*512);

  f32x16 o0 = {}, o1 = {};
  float m, l_part = 0.f;

  if (qidx < 63){
    // ============ FAST PATH: fixed m = 0, no max tracking ============
    m = 0.f;
    int kb_first = qw + wave*32;
    short8 kfc[4];
    if (kb_first < SEQ){
      int tk = (kb_first >> 5) * 4;
      #pragma unroll
      for (int kc = 0; kc < 4; kc++)
        kfc[kc] = *reinterpret_cast<const short8*>(Kf + (size_t)(tk + kc)*512);
    }
    for (int kb = kb_first; kb < SEQ; kb += 128){
      int tv = (kb >> 4) * 2;
      short8 vf0 = *reinterpret_cast<const short8*>(Vf + (size_t)(tv + 0)*512);
      short8 vf1 = *reinterpret_cast<const short8*>(Vf + (size_t)(tv + 1)*512);
      short8 vf2 = *reinterpret_cast<const short8*>(Vf + (size_t)(tv + 2)*512);
      short8 vf3 = *reinterpret_cast<const short8*>(Vf + (size_t)(tv + 3)*512);
      int kbn = kb + 128;
      int tkn = ((kbn < SEQ ? kbn : kb) >> 5) * 4;
      short8 kfn[4];
      #pragma unroll
      for (int kc = 0; kc < 4; kc++)
        kfn[kc] = *reinterpret_cast<const short8*>(Kf + (size_t)(tkn + kc)*512);
      f32x16 s0 = {};
      __builtin_amdgcn_s_setprio(1);
      #pragma unroll
      for (int kc = 0; kc < 4; kc++)
        s0 = __builtin_amdgcn_mfma_f32_32x32x16_bf16(kfc[kc], qf[kc], s0, 0, 0, 0);
      __builtin_amdgcn_s_setprio(0);
      if (kb <= qw + 31){     // first step of wave 0 only
        #pragma unroll
        for (int r = 0; r < 16; r++){
          int kv = kb + 4*hi + (r & 3) + 8*(r >> 2);
          s0[r] += (kv <= qg) ? NEGL : 0.f;
        }
      }
      float ps = 0.f;
      #pragma unroll
      for (int r = 0; r < 16; r++){
        s0[r] = fexp2(s0[r]);
        ps += s0[r];
      }
      l_part += ps;
      short8 pa0 = pack_pa<0>(s0), pa1 = pack_pa<8>(s0);
      __builtin_amdgcn_s_setprio(1);
      o0 = __builtin_amdgcn_mfma_f32_32x32x16_bf16(pa0, vf0, o0, 0, 0, 0);
      o1 = __builtin_amdgcn_mfma_f32_32x32x16_bf16(pa0, vf1, o1, 0, 0, 0);
      o0 = __builtin_amdgcn_mfma_f32_32x32x16_bf16(pa1, vf2, o0, 0, 0, 0);
      o1 = __builtin_amdgcn_mfma_f32_32x32x16_bf16(pa1, vf3, o1, 0, 0, 0);
      __builtin_amdgcn_s_setprio(0);
      #pragma unroll
      for (int kc = 0; kc < 4; kc++) kfc[kc] = kfn[kc];
    }
  } else {
    // ============ FULL PATH (tile 63): m-tracked, proven ============
    m = -INFINITY;
    int kb_first = wave*32;
    short8 kfc[4];
    {
      int tk = (kb_first >> 5) * 4;
      #pragma unroll
      for (int kc = 0; kc < 4; kc++)
        kfc[kc] = *reinterpret_cast<const short8*>(Kf + (size_t)(tk + kc)*512);
    }
    for (int kb = kb_first; kb < SEQ; kb += 128){
      int tv = (kb >> 4) * 2;
      short8 vf0 = *reinterpret_cast<const short8*>(Vf + (size_t)(tv + 0)*512);
      short8 vf1 = *reinterpret_cast<const short8*>(Vf + (size_t)(tv + 1)*512);
      short8 vf2 = *reinterpret_cast<const short8*>(Vf + (size_t)(tv + 2)*512);
      short8 vf3 = *reinterpret_cast<const short8*>(Vf + (size_t)(tv + 3)*512);
      int kbn = kb + 128;
      int tkn = ((kbn < SEQ ? kbn : kb) >> 5) * 4;
      short8 kfn[4];
      #pragma unroll
      for (int kc = 0; kc < 4; kc++)
        kfn[kc] = *reinterpret_cast<const short8*>(Kf + (size_t)(tkn + kc)*512);
      f32x16 s0 = {};
      __builtin_amdgcn_s_setprio(1);
      #pragma unroll
      for (int kc = 0; kc < 4; kc++)
        s0 = __builtin_amdgcn_mfma_f32_32x32x16_bf16(kfc[kc], qf[kc], s0, 0, 0, 0);
      __builtin_amdgcn_s_setprio(0);
      // tile 63: mask applies on every step (rows 2016..2047 mask j<=i)
      #pragma unroll
      for (int r = 0; r < 16; r++){
        int kv = kb + 4*hi + (r & 3) + 8*(r >> 2);
        s0[r] += (kv <= qg) ? NEGL : 0.f;
      }
      float t0 = fmaxf(fmaxf(s0[0], s0[4]), fmaxf(s0[8],  s0[12]));
      float t1 = fmaxf(fmaxf(s0[1], s0[5]), fmaxf(s0[9],  s0[13]));
      float t2 = fmaxf(fmaxf(s0[2], s0[6]), fmaxf(s0[10], s0[14]));
      float t3 = fmaxf(fmaxf(s0[3], s0[7]), fmaxf(s0[11], s0[15]));
      float pmx = fmaxf(fmaxf(t0, t1), fmaxf(t2, t3));
      if (__any(pmx > m + 8.0f)){
        float pmf = fmaxf(pmx, __shfl_xor(pmx, 32));
        float mn = fmaxf(m, pmf);
        float al = fexp2(m - mn);
        #pragma unroll
        for (int r = 0; r < 16; r++){
          float alr = __shfl(al, (r & 3) + 8*(r >> 2) + 4*hi);
          o0[r] *= alr; o1[r] *= alr;
        }
        l_part *= al;
        m = mn;
      }
      float negm = -m;
      float ps = 0.f;
      #pragma unroll
      for (int r = 0; r < 16; r++){
        s0[r] = fexp2(s0[r] + negm);
        ps += s0[r];
      }
      l_part += ps;
      short8 pa0 = pack_pa<0>(s0), pa1 = pack_pa<8>(s0);
      __builtin_amdgcn_s_setprio(1);
      o0 = __builtin_amdgcn_mfma_f32_32x32x16_bf16(pa0, vf0, o0, 0, 0, 0);
      o1 = __builtin_amdgcn_mfma_f32_32x32x16_bf16(pa0, vf1, o1, 0, 0, 0);
      o0 = __builtin_amdgcn_mfma_f32_32x32x16_bf16(pa1, vf2, o0, 0, 0, 0);
      o1 = __builtin_amdgcn_mfma_f32_32x32x16_bf16(pa1, vf3, o1, 0, 0, 0);
      __builtin_amdgcn_s_setprio(0);
      #pragma unroll
      for (int kc = 0; kc < 4; kc++) kfc[kc] = kfn[kc];
    }
  }

  // ---- complete l: one cross-half exchange after the loop ----
  float l = l_part + __shfl_xor(l_part, 32);

  // ---- write per-wave partial state to LDS (O in bf16) ----
  #pragma unroll
  for (int r = 0; r < 16; r++){
    int row = (r & 3) + 8*(r >> 2) + 4*hi;
    po[wave][row][ln]      = f2bf(o0[r]);
    po[wave][row][32 + ln] = f2bf(o1[r]);
  }
  if (hi == 0){ pmv[wave][ln] = m; plv[wave][ln] = l; }
  __syncthreads();

  // ---- flash-combine 4 partials; 256 threads cover 32 rows x 64 cols ----
  int t   = threadIdx.x;
  int row = t >> 3;
  int c8  = (t & 7) * 8;
  float m0 = pmv[0][row], m1 = pmv[1][row], m2 = pmv[2][row], m3 = pmv[3][row];
  float ms = fmaxf(fmaxf(m0, m1), fmaxf(m2, m3));
  float f0 = fexp2(m0 - ms), f1 = fexp2(m1 - ms);
  float f2 = fexp2(m2 - ms), f3 = fexp2(m3 - ms);
  float ls = plv[0][row]*f0 + plv[1][row]*f1 + plv[2][row]*f2 + plv[3][row]*f3;
  float inv = 1.0f / ls;
  f0 *= inv; f1 *= inv; f2 *= inv; f3 *= inv;
  int b = bh >> 4, h = bh & 15;
  u16 tmp[8];
  #pragma unroll
  for (int i = 0; i < 8; i += 4){
    ushort4 w0 = *reinterpret_cast<const ushort4*>(&po[0][row][c8 + i]);
    ushort4 w1 = *reinterpret_cast<const ushort4*>(&po[1][row][c8 + i]);
    ushort4 w2 = *reinterpret_cast<const ushort4*>(&po[2][row][c8 + i]);
    ushort4 w3 = *reinterpret_cast<const ushort4*>(&po[3][row][c8 + i]);
    const u16* p0 = (const u16*)&w0; const u16* p1 = (const u16*)&w1;
    const u16* p2 = (const u16*)&w2; const u16* p3 = (const u16*)&w3;
    #pragma unroll
    for (int j = 0; j < 4; j++){
      float v = __builtin_bit_cast(float, (unsigned)p0[j] << 16) * f0
              + __builtin_bit_cast(float, (unsigned)p1[j] << 16) * f1
              + __builtin_bit_cast(float, (unsigned)p2[j] << 16) * f2
              + __builtin_bit_cast(float, (unsigned)p3[j] << 16) * f3;
      tmp[i + j] = f2bf(v);
    }
  }
  u16* dst = vals + ((size_t)(b * SEQ + qw + row)) * EMBED + h * HD + c8;
  *reinterpret_cast<ushort4*>(dst)     = *reinterpret_cast<ushort4*>(&tmp[0]);
  *reinterpret_cast<ushort4*>(dst + 4) = *reinterpret_cast<ushort4*>(&tmp[4]);
}

// ---------------- GEMM2 (m97 structure): out = vals @ Wout + b ----------------
// 64x128 tile, BK=32, 4 waves (2x2), wave tile 32x64. Grid 512 blocks.
__global__ __launch_bounds__(256) void k_gemm_out(
    const u16* __restrict__ A, const u16* __restrict__ Bt,
    const float* __restrict__ bias, float* __restrict__ out)
{
  const int K = 1024;
  __shared__ __align__(16) u16 As[64*32];
  __shared__ __align__(16) u16 Bs[128*32];
  int t = threadIdx.x;
  int wave = t >> 6, lane = t & 63;
  int g = lane >> 4, c = lane & 15;
  int wr = wave >> 1, wc = wave & 1;
  int mb = blockIdx.y * 64, nb = blockIdx.x * 128;

  const u16* ga = A  + (size_t)(mb + wave*16 + (lane>>2)) * K + (lane&3)*8;
  const u16* gb = Bt + (size_t)(nb + wave*32 + (lane>>2)) * K + (lane&3)*8;
  u16* la = &As[wave*512];
  u16* lb = &Bs[wave*1024];

  f32x4 acc[2][4] = {};
  for (int k = 0; k < K; k += 32){
    gload16(ga + k,          la);
    gload16(gb + k,          lb);
    gload16(gb + k + 16*K,   lb + 512);
    __syncthreads();
    short8 af[2], bf[4];
    #pragma unroll
    for (int i = 0; i < 2; i++)
      af[i] = *reinterpret_cast<const short8*>(&As[(wr*32 + i*16 + c)*32 + 8*g]);
    #pragma unroll
    for (int j = 0; j < 4; j++)
      bf[j] = *reinterpret_cast<const short8*>(&Bs[(wc*64 + j*16 + c)*32 + 8*g]);
    #pragma unroll
    for (int i = 0; i < 2; i++)
      #pragma unroll
      for (int j = 0; j < 4; j++)
        acc[i][j] = __builtin_amdgcn_mfma_f32_16x16x32_bf16(af[i], bf[j], acc[i][j], 0, 0, 0);
    __syncthreads();
  }

  #pragma unroll
  for (int i = 0; i < 2; i++)
  #pragma unroll
  for (int j = 0; j < 4; j++)
  #pragma unroll
  for (int r = 0; r < 4; r++){
    int row = mb + wr*32 + i*16 + 4*g + r;
    int col = nb + wc*64 + j*16 + c;
    out[(size_t)row * EMBED + col] = acc[i][j][r] + bias[col];
  }
}

extern "C" void kernel_launch(void* const* d_in, const int* in_sizes, int n_in,
                              void* d_out, int out_size, void* d_ws, size_t ws_size,
                              hipStream_t stream){
  const float* x    = (const float*)d_in[0];
  const float* Wqkv = (const float*)d_in[1];
  const float* bqkv = (const float*)d_in[2];
  const float* Wout = (const float*)d_in[3];
  const float* bout = (const float*)d_in[4];
  float* out = (float*)d_out;

  char* ws = (char*)d_ws;
  u16* x_bf   = (u16*)(ws);                       // 8 MB
  u16* wqkv_t = (u16*)(ws + ( 8u << 20));         // 6 MB
  u16* wout_t = (u16*)(ws + (14u << 20));         // 2 MB
  u16* qbuf   = (u16*)(ws + (16u << 20));         // 8 MB (fragment order, Q pre-scaled)
  u16* kbuf   = (u16*)(ws + (24u << 20));         // 8 MB (fragment order)
  u16* vtbuf  = (u16*)(ws + (32u << 20));         // 8 MB (fragment order)
  u16* vals   = (u16*)(ws + (40u << 20));         // 8 MB   (48 MB total)

  k_cvt<<<4096, 256, 0, stream>>>(x, x_bf);
  dim3 tb(32, 8);
  k_transpose<<<dim3(3072/32, 1024/32), tb, 0, stream>>>(Wqkv, wqkv_t, 1024, 3072);
  k_transpose<<<dim3(1024/32, 1024/32), tb, 0, stream>>>(Wout, wout_t, 1024, 1024);
  k_gemm_qkv<<<dim3(3072/128, 4096/128), 256, 0, stream>>>(x_bf, wqkv_t, bqkv, qbuf, kbuf, vtbuf);
  k_attn<<<2048, 256, 0, stream>>>(qbuf, kbuf, vtbuf, vals);
  k_gemm_out<<<dim3(1024/128, 4096/64), 256, 0, stream>>>(vals, wout_t, bout, out);
}

// Round 19
// 109.630 us; speedup vs baseline: 1.1640x; 1.1640x over previous
//
#include <hip/hip_runtime.h>
#include <hip/hip_bf16.h>

#define BATCH 2
#define SEQ 2048
#define EMBED 1024
#define HEADS 16
#define HD 64

typedef __attribute__((ext_vector_type(8))) short short8;
typedef __attribute__((ext_vector_type(4))) float f32x4;
typedef __attribute__((ext_vector_type(16))) float f32x16;
typedef __attribute__((ext_vector_type(4))) int i32x4;
typedef unsigned short u16;

// log2-domain softmax constants: scale' = 0.125*log2(e); mask' = -1e9*log2(e)
#define C2F 0.18033688f
#define NEGL -1442695040.0f

__device__ __forceinline__ u16 f2bf(float x){
  unsigned u = __builtin_bit_cast(unsigned, x);
  u = (u + 0x7fffu + ((u >> 16) & 1u)) >> 16;
  return (u16)u;
}

// raw v_exp_f32: valid here because inputs are either normal-range or hugely
// negative (masked: flush-to-zero is exactly the reference fp32 behavior).
__device__ __forceinline__ float fexp2(float x){
  float r;
  asm("v_exp_f32 %0, %1" : "=v"(r) : "v"(x));
  return r;
}

// async global->LDS, 16B per lane; dest = wave-uniform base + lane*16
__device__ __forceinline__ void gload16(const u16* g, u16* l){
  __builtin_amdgcn_global_load_lds(
      (const __attribute__((address_space(1))) unsigned int*)g,
      (__attribute__((address_space(3))) unsigned int*)l, 16, 0, 0);
}

// ---------------- x fp32 -> bf16 (vectorized) ----------------
__global__ void k_cvt(const float* __restrict__ in, u16* __restrict__ out){
  int i = blockIdx.x * blockDim.x + threadIdx.x;
  float4 v = reinterpret_cast<const float4*>(in)[i];
  ushort4 o;
  o.x = f2bf(v.x); o.y = f2bf(v.y); o.z = f2bf(v.z); o.w = f2bf(v.w);
  reinterpret_cast<ushort4*>(out)[i] = o;
}

// ---------------- transpose [K][N] fp32 -> [N][K] bf16 ----------------
__global__ void k_transpose(const float* __restrict__ in, u16* __restrict__ out,
                            int K, int N){
  __shared__ float tile[32][33];
  int n0 = blockIdx.x * 32, k0 = blockIdx.y * 32;
  int tx = threadIdx.x, ty = threadIdx.y;   // block (32,8)
  #pragma unroll
  for (int i = 0; i < 32; i += 8)
    tile[ty + i][tx] = in[(size_t)(k0 + ty + i) * N + n0 + tx];
  __syncthreads();
  #pragma unroll
  for (int i = 0; i < 32; i += 8)
    out[(size_t)(n0 + ty + i) * K + k0 + tx] = f2bf(tile[tx][ty + i]);
}

// ---------------- GEMM1 (m97 structure): qkv = x@Wqkv + b ----------------
// BK=32, linear block order (round-16 configuration — best measured).
// Q/K/V scattered into MFMA-FRAGMENT order via the LDS-staged full-line
// epilogue; Q pre-scaled by C2F so k_attn's QK^T lands in log2 domain.
__global__ __launch_bounds__(256) void k_gemm_qkv(
    const u16* __restrict__ A, const u16* __restrict__ Bt,
    const float* __restrict__ bias,
    u16* __restrict__ qb, u16* __restrict__ kbf, u16* __restrict__ vt)
{
  const int K = 1024;
  __shared__ __align__(16) u16 sbuf[128*144];   // As(8KB)+Bs(8KB) / Cs(36.8KB)
  u16* As = sbuf;
  u16* Bs = sbuf + 4096;
  int t = threadIdx.x;
  int wave = t >> 6, lane = t & 63;
  int g = lane >> 4, c = lane & 15;
  int wr = wave >> 1, wc = wave & 1;
  int mb = blockIdx.y * 128, nb = blockIdx.x * 128;

  const u16* ga = A  + (size_t)(mb + wave*32 + (lane>>2)) * K + (lane&3)*8;
  const u16* gb = Bt + (size_t)(nb + wave*32 + (lane>>2)) * K + (lane&3)*8;
  u16* la = &As[wave*1024];
  u16* lb = &Bs[wave*1024];

  f32x4 acc[4][4] = {};
  for (int k = 0; k < K; k += 32){
    gload16(ga + k,          la);
    gload16(ga + k + 16*K,   la + 512);
    gload16(gb + k,          lb);
    gload16(gb + k + 16*K,   lb + 512);
    __syncthreads();
    short8 af[4], bf[4];
    #pragma unroll
    for (int i = 0; i < 4; i++){
      af[i] = *reinterpret_cast<const short8*>(&As[(wr*64 + i*16 + c)*32 + 8*g]);
      bf[i] = *reinterpret_cast<const short8*>(&Bs[(wc*64 + i*16 + c)*32 + 8*g]);
    }
    #pragma unroll
    for (int i = 0; i < 4; i++)
      #pragma unroll
      for (int j = 0; j < 4; j++)
        acc[i][j] = __builtin_amdgcn_mfma_f32_16x16x32_bf16(af[i], bf[j], acc[i][j], 0, 0, 0);
    __syncthreads();
  }

  // ---- stage C (bf16, bias added; Q cols pre-scaled by C2F) into LDS ----
  u16 (*Cs)[144] = (u16(*)[144])sbuf;
  #pragma unroll
  for (int i = 0; i < 4; i++)
  #pragma unroll
  for (int j = 0; j < 4; j++)
  #pragma unroll
  for (int r = 0; r < 4; r++){
    int row = wr*64 + i*16 + 4*g + r;
    int col = wc*64 + j*16 + c;
    int gcol = nb + col;
    float vv = acc[i][j][r] + bias[gcol];
    if ((gcol % 192) < 64) vv *= C2F;     // Q column
    Cs[row][col] = f2bf(vv);
  }
  __syncthreads();

  // ---- fragment-run writes: 32 cells x 64 runs of 16B ----
  int b  = mb >> 11;
  int sb = mb & 2047;
  for (int cell = wave; cell < 32; cell += 4){
    int s32 = cell >> 3;          // 0..3 (32-row group)
    int cg  = cell & 7;           // 0..7 (16-col group)
    int col0 = nb + cg*16;
    int h   = col0 / 192;
    int rem = col0 - h*192;
    int sel = rem >> 6;
    int d0  = rem & 63;           // 16-aligned
    size_t hb = (size_t)(b * HEADS + h);
    if (sel < 2){
      int sl  = lane & 31;
      int dhi = lane >> 5;
      int s   = sb + s32*32 + sl;
      size_t off = (((hb*64 + (size_t)(s>>5))*4 + (size_t)(d0>>4))*64 + (size_t)lane)*8;
      const short8 v = *reinterpret_cast<const short8*>(&Cs[s32*32 + sl][cg*16 + dhi*8]);
      u16* dst = (sel == 0 ? qb : kbf) + off;
      *reinterpret_cast<short8*>(dst) = v;
    } else {
      int dl   = lane & 15;
      int soct = lane >> 4;       // 0..3
      int d    = d0 + dl;
      int sl0  = s32*32 + soct*8;
      int s0   = sb + sl0;
      int lanep = (d & 31) | (((s0 >> 3) & 1) << 5);
      size_t off = (((hb*128 + (size_t)(s0>>4))*2 + (size_t)(d>>5))*64 + (size_t)lanep)*8;
      u16 tmp[8];
      #pragma unroll
      for (int k2 = 0; k2 < 8; k2++) tmp[k2] = Cs[sl0 + k2][cg*16 + dl];
      *reinterpret_cast<short8*>(vt + off) = *reinterpret_cast<const short8*>(tmp);
    }
  }
}

// ---------------- P-fragment pack: cvt_pk + permlane32_swap (T12) ----------------
template<int B>
__device__ __forceinline__ short8 pack_pa(const f32x16& p){
  unsigned X, Y, Z, W;
  asm("v_cvt_pk_bf16_f32 %0, %1, %2" : "=v"(X) : "v"(p[B+0]), "v"(p[B+1]));
  asm("v_cvt_pk_bf16_f32 %0, %1, %2" : "=v"(Y) : "v"(p[B+2]), "v"(p[B+3]));
  asm("v_cvt_pk_bf16_f32 %0, %1, %2" : "=v"(Z) : "v"(p[B+4]), "v"(p[B+5]));
  asm("v_cvt_pk_bf16_f32 %0, %1, %2" : "=v"(W) : "v"(p[B+6]), "v"(p[B+7]));
  asm("v_permlane32_swap_b32 %0, %1" : "+v"(X), "+v"(Z));
  asm("v_permlane32_swap_b32 %0, %1" : "+v"(Y), "+v"(W));
  i32x4 w = { (int)X, (int)Y, (int)Z, (int)W };
  return __builtin_bit_cast(short8, w);
}

// ---------------- fused anti-causal flash attention, swapped-QK 32x32 ----------
// (round-16 version — best passing)
__global__ __launch_bounds__(256) void k_attn(
    const u16* __restrict__ qb, const u16* __restrict__ kbuf,
    const u16* __restrict__ vt, u16* __restrict__ vals)
{
  __shared__ __align__(16) u16 po[4][32][72];   // bf16 partial O, row-padded
  __shared__ float pmv[4][32];
  __shared__ float plv[4][32];

  int wave = threadIdx.x >> 6, lane = threadIdx.x & 63;
  int hi = lane >> 5, ln = lane & 31;
  int d0 = blockIdx.x;
  int x   = d0 & 7;
  int kk  = d0 >> 3;            // [0,256)
  int grp = kk >> 6;            // [0,4)
  int qr  = kk & 63;
  int qidx = (qr == 0) ? 63 : qr - 1;
  int bh  = x + 8 * grp;
  int qw  = qidx * 32;
  int qg  = qw + ln;

  // fragment-space base pointers (each bh = 256 tiles x 512 u16 = 256KB)
  const u16* Qf = qb   + (size_t)bh*131072 + ((size_t)(qw>>5)*4)*512 + (size_t)lane*8;
  const u16* Kf = kbuf + (size_t)bh*131072 + (size_t)lane*8;
  const u16* Vf = vt   + (size_t)bh*131072 + (size_t)lane*8;

  short8 qf[4];
  #pragma unroll
  for (int kc = 0; kc < 4; kc++)
    qf[kc] = *reinterpret_cast<const short8*>(Qf + (size_t)kc*512);

  f32x16 o0 = {}, o1 = {};
  float m, l_part = 0.f;

  if (qidx < 63){
    // ============ FAST PATH: fixed m = 0, no max tracking ============
    m = 0.f;
    int kb_first = qw + wave*32;
    short8 kfc[4];
    if (kb_first < SEQ){
      int tk = (kb_first >> 5) * 4;
      #pragma unroll
      for (int kc = 0; kc < 4; kc++)
        kfc[kc] = *reinterpret_cast<const short8*>(Kf + (size_t)(tk + kc)*512);
    }
    for (int kb = kb_first; kb < SEQ; kb += 128){
      int tv = (kb >> 4) * 2;
      short8 vf0 = *reinterpret_cast<const short8*>(Vf + (size_t)(tv + 0)*512);
      short8 vf1 = *reinterpret_cast<const short8*>(Vf + (size_t)(tv + 1)*512);
      short8 vf2 = *reinterpret_cast<const short8*>(Vf + (size_t)(tv + 2)*512);
      short8 vf3 = *reinterpret_cast<const short8*>(Vf + (size_t)(tv + 3)*512);
      int kbn = kb + 128;
      int tkn = ((kbn < SEQ ? kbn : kb) >> 5) * 4;
      short8 kfn[4];
      #pragma unroll
      for (int kc = 0; kc < 4; kc++)
        kfn[kc] = *reinterpret_cast<const short8*>(Kf + (size_t)(tkn + kc)*512);
      f32x16 s0 = {};
      __builtin_amdgcn_s_setprio(1);
      #pragma unroll
      for (int kc = 0; kc < 4; kc++)
        s0 = __builtin_amdgcn_mfma_f32_32x32x16_bf16(kfc[kc], qf[kc], s0, 0, 0, 0);
      __builtin_amdgcn_s_setprio(0);
      if (kb <= qw + 31){     // first step of wave 0 only
        #pragma unroll
        for (int r = 0; r < 16; r++){
          int kv = kb + 4*hi + (r & 3) + 8*(r >> 2);
          s0[r] += (kv <= qg) ? NEGL : 0.f;
        }
      }
      float ps = 0.f;
      #pragma unroll
      for (int r = 0; r < 16; r++){
        s0[r] = fexp2(s0[r]);
        ps += s0[r];
      }
      l_part += ps;
      short8 pa0 = pack_pa<0>(s0), pa1 = pack_pa<8>(s0);
      __builtin_amdgcn_s_setprio(1);
      o0 = __builtin_amdgcn_mfma_f32_32x32x16_bf16(pa0, vf0, o0, 0, 0, 0);
      o1 = __builtin_amdgcn_mfma_f32_32x32x16_bf16(pa0, vf1, o1, 0, 0, 0);
      o0 = __builtin_amdgcn_mfma_f32_32x32x16_bf16(pa1, vf2, o0, 0, 0, 0);
      o1 = __builtin_amdgcn_mfma_f32_32x32x16_bf16(pa1, vf3, o1, 0, 0, 0);
      __builtin_amdgcn_s_setprio(0);
      #pragma unroll
      for (int kc = 0; kc < 4; kc++) kfc[kc] = kfn[kc];
    }
  } else {
    // ============ FULL PATH (tile 63): m-tracked, proven ============
    m = -INFINITY;
    int kb_first = wave*32;
    short8 kfc[4];
    {
      int tk = (kb_first >> 5) * 4;
      #pragma unroll
      for (int kc = 0; kc < 4; kc++)
        kfc[kc] = *reinterpret_cast<const short8*>(Kf + (size_t)(tk + kc)*512);
    }
    for (int kb = kb_first; kb < SEQ; kb += 128){
      int tv = (kb >> 4) * 2;
      short8 vf0 = *reinterpret_cast<const short8*>(Vf + (size_t)(tv + 0)*512);
      short8 vf1 = *reinterpret_cast<const short8*>(Vf + (size_t)(tv + 1)*512);
      short8 vf2 = *reinterpret_cast<const short8*>(Vf + (size_t)(tv + 2)*512);
      short8 vf3 = *reinterpret_cast<const short8*>(Vf + (size_t)(tv + 3)*512);
      int kbn = kb + 128;
      int tkn = ((kbn < SEQ ? kbn : kb) >> 5) * 4;
      short8 kfn[4];
      #pragma unroll
      for (int kc = 0; kc < 4; kc++)
        kfn[kc] = *reinterpret_cast<const short8*>(Kf + (size_t)(tkn + kc)*512);
      f32x16 s0 = {};
      __builtin_amdgcn_s_setprio(1);
      #pragma unroll
      for (int kc = 0; kc < 4; kc++)
        s0 = __builtin_amdgcn_mfma_f32_32x32x16_bf16(kfc[kc], qf[kc], s0, 0, 0, 0);
      __builtin_amdgcn_s_setprio(0);
      // tile 63: mask applies on every step (rows 2016..2047 mask j<=i)
      #pragma unroll
      for (int r = 0; r < 16; r++){
        int kv = kb + 4*hi + (r & 3) + 8*(r >> 2);
        s0[r] += (kv <= qg) ? NEGL : 0.f;
      }
      float t0 = fmaxf(fmaxf(s0[0], s0[4]), fmaxf(s0[8],  s0[12]));
      float t1 = fmaxf(fmaxf(s0[1], s0[5]), fmaxf(s0[9],  s0[13]));
      float t2 = fmaxf(fmaxf(s0[2], s0[6]), fmaxf(s0[10], s0[14]));
      float t3 = fmaxf(fmaxf(s0[3], s0[7]), fmaxf(s0[11], s0[15]));
      float pmx = fmaxf(fmaxf(t0, t1), fmaxf(t2, t3));
      if (__any(pmx > m + 8.0f)){
        float pmf = fmaxf(pmx, __shfl_xor(pmx, 32));
        float mn = fmaxf(m, pmf);
        float al = fexp2(m - mn);
        #pragma unroll
        for (int r = 0; r < 16; r++){
          float alr = __shfl(al, (r & 3) + 8*(r >> 2) + 4*hi);
          o0[r] *= alr; o1[r] *= alr;
        }
        l_part *= al;
        m = mn;
      }
      float negm = -m;
      float ps = 0.f;
      #pragma unroll
      for (int r = 0; r < 16; r++){
        s0[r] = fexp2(s0[r] + negm);
        ps += s0[r];
      }
      l_part += ps;
      short8 pa0 = pack_pa<0>(s0), pa1 = pack_pa<8>(s0);
      __builtin_amdgcn_s_setprio(1);
      o0 = __builtin_amdgcn_mfma_f32_32x32x16_bf16(pa0, vf0, o0, 0, 0, 0);
      o1 = __builtin_amdgcn_mfma_f32_32x32x16_bf16(pa0, vf1, o1, 0, 0, 0);
      o0 = __builtin_amdgcn_mfma_f32_32x32x16_bf16(pa1, vf2, o0, 0, 0, 0);
      o1 = __builtin_amdgcn_mfma_f32_32x32x16_bf16(pa1, vf3, o1, 0, 0, 0);
      __builtin_amdgcn_s_setprio(0);
      #pragma unroll
      for (int kc = 0; kc < 4; kc++) kfc[kc] = kfn[kc];
    }
  }

  // ---- complete l: one cross-half exchange after the loop ----
  float l = l_part + __shfl_xor(l_part, 32);

  // ---- write per-wave partial state to LDS (O in bf16) ----
  #pragma unroll
  for (int r = 0; r < 16; r++){
    int row = (r & 3) + 8*(r >> 2) + 4*hi;
    po[wave][row][ln]      = f2bf(o0[r]);
    po[wave][row][32 + ln] = f2bf(o1[r]);
  }
  if (hi == 0){ pmv[wave][ln] = m; plv[wave][ln] = l; }
  __syncthreads();

  // ---- flash-combine 4 partials; 256 threads cover 32 rows x 64 cols ----
  int t   = threadIdx.x;
  int row = t >> 3;
  int c8  = (t & 7) * 8;
  float m0 = pmv[0][row], m1 = pmv[1][row], m2 = pmv[2][row], m3 = pmv[3][row];
  float ms = fmaxf(fmaxf(m0, m1), fmaxf(m2, m3));
  float f0 = fexp2(m0 - ms), f1 = fexp2(m1 - ms);
  float f2 = fexp2(m2 - ms), f3 = fexp2(m3 - ms);
  float ls = plv[0][row]*f0 + plv[1][row]*f1 + plv[2][row]*f2 + plv[3][row]*f3;
  float inv = 1.0f / ls;
  f0 *= inv; f1 *= inv; f2 *= inv; f3 *= inv;
  int b = bh >> 4, h = bh & 15;
  u16 tmp[8];
  #pragma unroll
  for (int i = 0; i < 8; i += 4){
    ushort4 w0 = *reinterpret_cast<const ushort4*>(&po[0][row][c8 + i]);
    ushort4 w1 = *reinterpret_cast<const ushort4*>(&po[1][row][c8 + i]);
    ushort4 w2 = *reinterpret_cast<const ushort4*>(&po[2][row][c8 + i]);
    ushort4 w3 = *reinterpret_cast<const ushort4*>(&po[3][row][c8 + i]);
    const u16* p0 = (const u16*)&w0; const u16* p1 = (const u16*)&w1;
    const u16* p2 = (const u16*)&w2; const u16* p3 = (const u16*)&w3;
    #pragma unroll
    for (int j = 0; j < 4; j++){
      float v = __builtin_bit_cast(float, (unsigned)p0[j] << 16) * f0
              + __builtin_bit_cast(float, (unsigned)p1[j] << 16) * f1
              + __builtin_bit_cast(float, (unsigned)p2[j] << 16) * f2
              + __builtin_bit_cast(float, (unsigned)p3[j] << 16) * f3;
      tmp[i + j] = f2bf(v);
    }
  }
  u16* dst = vals + ((size_t)(b * SEQ + qw + row)) * EMBED + h * HD + c8;
  *reinterpret_cast<ushort4*>(dst)     = *reinterpret_cast<ushort4*>(&tmp[0]);
  *reinterpret_cast<ushort4*>(dst + 4) = *reinterpret_cast<ushort4*>(&tmp[4]);
}

// ---------------- GEMM2 (m97 structure): out = vals @ Wout + b ----------------
// 64x128 tile, BK=32, 4 waves (2x2), wave tile 32x64. Grid 512 blocks.
__global__ __launch_bounds__(256) void k_gemm_out(
    const u16* __restrict__ A, const u16* __restrict__ Bt,
    const float* __restrict__ bias, float* __restrict__ out)
{
  const int K = 1024;
  __shared__ __align__(16) u16 As[64*32];
  __shared__ __align__(16) u16 Bs[128*32];
  int t = threadIdx.x;
  int wave = t >> 6, lane = t & 63;
  int g = lane >> 4, c = lane & 15;
  int wr = wave >> 1, wc = wave & 1;
  int mb = blockIdx.y * 64, nb = blockIdx.x * 128;

  const u16* ga = A  + (size_t)(mb + wave*16 + (lane>>2)) * K + (lane&3)*8;
  const u16* gb = Bt + (size_t)(nb + wave*32 + (lane>>2)) * K + (lane&3)*8;
  u16* la = &As[wave*512];
  u16* lb = &Bs[wave*1024];

  f32x4 acc[2][4] = {};
  for (int k = 0; k < K; k += 32){
    gload16(ga + k,          la);
    gload16(gb + k,          lb);
    gload16(gb + k + 16*K,   lb + 512);
    __syncthreads();
    short8 af[2], bf[4];
    #pragma unroll
    for (int i = 0; i < 2; i++)
      af[i] = *reinterpret_cast<const short8*>(&As[(wr*32 + i*16 + c)*32 + 8*g]);
    #pragma unroll
    for (int j = 0; j < 4; j++)
      bf[j] = *reinterpret_cast<const short8*>(&Bs[(wc*64 + j*16 + c)*32 + 8*g]);
    #pragma unroll
    for (int i = 0; i < 2; i++)
      #pragma unroll
      for (int j = 0; j < 4; j++)
        acc[i][j] = __builtin_amdgcn_mfma_f32_16x16x32_bf16(af[i], bf[j], acc[i][j], 0, 0, 0);
    __syncthreads();
  }

  #pragma unroll
  for (int i = 0; i < 2; i++)
  #pragma unroll
  for (int j = 0; j < 4; j++)
  #pragma unroll
  for (int r = 0; r < 4; r++){
    int row = mb + wr*32 + i*16 + 4*g + r;
    int col = nb + wc*64 + j*16 + c;
    out[(size_t)row * EMBED + col] = acc[i][j][r] + bias[col];
  }
}

extern "C" void kernel_launch(void* const* d_in, const int* in_sizes, int n_in,
                              void* d_out, int out_size, void* d_ws, size_t ws_size,
                              hipStream_t stream){
  const float* x    = (const float*)d_in[0];
  const float* Wqkv = (const float*)d_in[1];
  const float* bqkv = (const float*)d_in[2];
  const float* Wout = (const float*)d_in[3];
  const float* bout = (const float*)d_in[4];
  float* out = (float*)d_out;

  char* ws = (char*)d_ws;
  u16* x_bf   = (u16*)(ws);                       // 8 MB
  u16* wqkv_t = (u16*)(ws + ( 8u << 20));         // 6 MB
  u16* wout_t = (u16*)(ws + (14u << 20));         // 2 MB
  u16* qbuf   = (u16*)(ws + (16u << 20));         // 8 MB (fragment order, Q pre-scaled)
  u16* kbuf   = (u16*)(ws + (24u << 20));         // 8 MB (fragment order)
  u16* vtbuf  = (u16*)(ws + (32u << 20));         // 8 MB (fragment order)
  u16* vals   = (u16*)(ws + (40u << 20));         // 8 MB   (48 MB total)

  k_cvt<<<4096, 256, 0, stream>>>(x, x_bf);
  dim3 tb(32, 8);
  k_transpose<<<dim3(3072/32, 1024/32), tb, 0, stream>>>(Wqkv, wqkv_t, 1024, 3072);
  k_transpose<<<dim3(1024/32, 1024/32), tb, 0, stream>>>(Wout, wout_t, 1024, 1024);
  k_gemm_qkv<<<dim3(3072/128, 4096/128), 256, 0, stream>>>(x_bf, wqkv_t, bqkv, qbuf, kbuf, vtbuf);
  k_attn<<<2048, 256, 0, stream>>>(qbuf, kbuf, vtbuf, vals);
  k_gemm_out<<<dim3(1024/128, 4096/64), 256, 0, stream>>>(vals, wout_t, bout, out);
}